// Round 5
// baseline (268.698 us; speedup 1.0000x reference)
//
#include <hip/hip_runtime.h>
#include <cstddef>

#define D_MODEL   512
#define D_INNER   1024
#define D_STATE   16
#define DT_RANK   32
#define SEQ_L     1024
#define BATCH     2
#define NLAYER    2
#define M_ROWS    (BATCH * SEQ_L)   // 2048
#define NC        32                // scan chunks
#define LC        (SEQ_L / NC)      // 32 timesteps per chunk

typedef __bf16 bf16x8 __attribute__((ext_vector_type(8)));
typedef float  f32x4  __attribute__((ext_vector_type(4)));

__device__ __forceinline__ float softplus_f(float x) {
    return fmaxf(x, 0.f) + log1pf(expf(-fabsf(x)));
}
__device__ __forceinline__ float silu_f(float x) {
    return x / (1.f + __expf(-x));
}
__device__ __forceinline__ unsigned short f2bf(float f) {
    unsigned u = __float_as_uint(f);
    return (unsigned short)((u + 0x7fffu + ((u >> 16) & 1u)) >> 16);
}
__device__ __forceinline__ float bf2f(unsigned short v) {
    return __uint_as_float(((unsigned)v) << 16);
}
__device__ __forceinline__ unsigned pack_bf2(float lo, float hi) {
    return (unsigned)f2bf(lo) | ((unsigned)f2bf(hi) << 16);
}

// -------- embedding gather --------------------------------------------------
__global__ void embed_kernel(const int* __restrict__ ids,
                             const float* __restrict__ emb,
                             float* __restrict__ x) {
    int g = blockIdx.x * blockDim.x + threadIdx.x;
    int c = (g & 127) << 2;
    int m = g >> 7;
    int row = ids[m];
    *(float4*)&x[(size_t)m * D_MODEL + c] =
        *(const float4*)&emb[(size_t)row * D_MODEL + c];
}

// -------- rmsnorm (bf16 out, feeds MFMA in_proj) ----------------------------
__global__ __launch_bounds__(64) void rmsnorm_bf_kernel(const float* __restrict__ x,
                                                        const float* __restrict__ w,
                                                        unsigned short* __restrict__ out) {
    int row = blockIdx.x;
    int tid = threadIdx.x;
    const float* xp = x + (size_t)row * D_MODEL;
    float4 v0 = *(const float4*)&xp[tid * 4];
    float4 v1 = *(const float4*)&xp[256 + tid * 4];
    float ss = v0.x*v0.x + v0.y*v0.y + v0.z*v0.z + v0.w*v0.w
             + v1.x*v1.x + v1.y*v1.y + v1.z*v1.z + v1.w*v1.w;
    #pragma unroll
    for (int off = 32; off > 0; off >>= 1) ss += __shfl_xor(ss, off);
    float scale = rsqrtf(ss * (1.f / D_MODEL) + 1e-5f);
    float4 w0 = *(const float4*)&w[tid * 4];
    float4 w1 = *(const float4*)&w[256 + tid * 4];
    unsigned short* op = out + (size_t)row * D_MODEL;
    uint2 p0, p1;
    p0.x = pack_bf2(v0.x * scale * w0.x, v0.y * scale * w0.y);
    p0.y = pack_bf2(v0.z * scale * w0.z, v0.w * scale * w0.w);
    p1.x = pack_bf2(v1.x * scale * w1.x, v1.y * scale * w1.y);
    p1.y = pack_bf2(v1.z * scale * w1.z, v1.w * scale * w1.w);
    *(uint2*)&op[tid * 4] = p0;
    *(uint2*)&op[256 + tid * 4] = p1;
}

// ---- cast+transpose weights (batched over layers via z): W[K][N]->Wt[N][K] -
__global__ __launch_bounds__(256) void castT_kernel(const float* __restrict__ W,
                                                    unsigned short* __restrict__ Wt,
                                                    int K, int N) {
    W  += (size_t)blockIdx.z * K * N;
    Wt += (size_t)blockIdx.z * K * N;
    __shared__ float tile[32][33];
    int n0 = blockIdx.x * 32, k0 = blockIdx.y * 32;
    int tx = threadIdx.x & 31, ty = threadIdx.x >> 5;
    #pragma unroll
    for (int i = 0; i < 4; ++i)
        tile[ty + i*8][tx] = W[(size_t)(k0 + ty + i*8) * N + n0 + tx];
    __syncthreads();
    #pragma unroll
    for (int i = 0; i < 4; ++i)
        Wt[(size_t)(n0 + ty + i*8) * K + k0 + tx] = f2bf(tile[tx][ty + i*8]);
}

// -------- bf16 MFMA GEMM: A[M,K](bf16) @ Bt[N,K]^T --------------------------
// EPI 2: C(f32) += acc ; EPI 3: Cb(bf16) = acc
template<int EPI>
__global__ __launch_bounds__(256) void gemm_mfma(const unsigned short* __restrict__ A,
                                                 const unsigned short* __restrict__ Bt,
                                                 float* __restrict__ C,
                                                 unsigned short* __restrict__ Cb,
                                                 int K, int ldc) {
    __shared__ unsigned short As[64 * 64];
    __shared__ unsigned short Bs[64 * 64];
    int m0 = blockIdx.y * 64;
    int n0 = blockIdx.x * 64;
    int t = threadIdx.x;
    int lane = t & 63, wave = t >> 6;
    int wr = wave >> 1, wc = wave & 1;
    int srow = t >> 3;
    int sc8  = t & 7;
    f32x4 acc[2][2] = {};

    for (int k0 = 0; k0 < K; k0 += 64) {
        __syncthreads();
        #pragma unroll
        for (int i = 0; i < 2; ++i) {
            int row = i * 32 + srow;
            int csrc = sc8 ^ (row & 7);
            __builtin_amdgcn_global_load_lds(
                (const __attribute__((address_space(1))) void*)
                    &A[(size_t)(m0 + row) * K + k0 + csrc * 8],
                (__attribute__((address_space(3))) void*)
                    &As[row * 64 + sc8 * 8], 16, 0, 0);
            __builtin_amdgcn_global_load_lds(
                (const __attribute__((address_space(1))) void*)
                    &Bt[(size_t)(n0 + row) * K + k0 + csrc * 8],
                (__attribute__((address_space(3))) void*)
                    &Bs[row * 64 + sc8 * 8], 16, 0, 0);
        }
        __syncthreads();
        #pragma unroll
        for (int ks = 0; ks < 2; ++ks) {
            bf16x8 av[2], bv[2];
            #pragma unroll
            for (int f = 0; f < 2; ++f) {
                int ar = wr * 32 + f * 16 + (lane & 15);
                int ac = (ks * 4 + (lane >> 4)) ^ (ar & 7);
                av[f] = *reinterpret_cast<const bf16x8*>(&As[ar * 64 + ac * 8]);
                int br = wc * 32 + f * 16 + (lane & 15);
                int bc = (ks * 4 + (lane >> 4)) ^ (br & 7);
                bv[f] = *reinterpret_cast<const bf16x8*>(&Bs[br * 64 + bc * 8]);
            }
            #pragma unroll
            for (int fm = 0; fm < 2; ++fm)
                #pragma unroll
                for (int fn = 0; fn < 2; ++fn)
                    acc[fm][fn] = __builtin_amdgcn_mfma_f32_16x16x32_bf16(
                        av[fm], bv[fn], acc[fm][fn], 0, 0, 0);
        }
    }
    #pragma unroll
    for (int fm = 0; fm < 2; ++fm)
        #pragma unroll
        for (int fn = 0; fn < 2; ++fn) {
            int row = m0 + wr * 32 + fm * 16 + (lane >> 4) * 4;
            int col = n0 + wc * 32 + fn * 16 + (lane & 15);
            #pragma unroll
            for (int r = 0; r < 4; ++r) {
                if (EPI == 2) C[(size_t)(row + r) * ldc + col] += acc[fm][fn][r];
                else          Cb[(size_t)(row + r) * ldc + col] = f2bf(acc[fm][fn][r]);
            }
        }
}

// -------- x_proj with fused conv+SiLU on A: xdbl = silu(conv(xi)) @ xp_w ----
__global__ __launch_bounds__(256) void xproj_f(const unsigned short* __restrict__ xi,
                                               const float* __restrict__ cw,
                                               const float* __restrict__ cb,
                                               const float* __restrict__ Bw,
                                               float* __restrict__ Cc) {
    __shared__ float Bsh[64][68];
    __shared__ float Ash[4][64];
    int row0 = blockIdx.x * 4;
    int t = threadIdx.x;
    int tr = t >> 6, c = t & 63;
    int kk = t >> 2, cb4 = (t & 3) << 4;
    int l = (row0 + tr) & (SEQ_L - 1);
    float acc = 0.f;
    for (int k0 = 0; k0 < 1024; k0 += 64) {
        __syncthreads();
        #pragma unroll
        for (int j = 0; j < 4; ++j) {
            float4 v = *(const float4*)&Bw[(size_t)(k0 + kk) * 64 + cb4 + j * 4];
            *(float4*)&Bsh[kk][cb4 + j * 4] = v;
        }
        {
            int d = k0 + c;
            float4 w = *(const float4*)&cw[d * 4];
            const unsigned short* col = &xi[(size_t)(row0 + tr) * 2048 + d];
            float x3 = bf2f(col[0]);
            float x2 = (l >= 1) ? bf2f(col[-2048]) : 0.f;
            float x1 = (l >= 2) ? bf2f(col[-4096]) : 0.f;
            float x0 = (l >= 3) ? bf2f(col[-6144]) : 0.f;
            Ash[tr][c] = silu_f(cb[d] + w.x*x0 + w.y*x1 + w.z*x2 + w.w*x3);
        }
        __syncthreads();
        #pragma unroll
        for (int k = 0; k < 64; ++k)
            acc = fmaf(Ash[tr][k], Bsh[k][c], acc);
    }
    Cc[(size_t)(row0 + tr) * 64 + c] = acc;
}

// ======================= chunk-parallel selective scan =======================
// dt = softplus(xdbl[:, :32] @ dt_w + dt_b) and u = silu(conv(xi)+cb) are
// recomputed identically in p1 and p3 (bit-exact), so no delta/u buffers.
__global__ __launch_bounds__(256) void scan_p1f(const unsigned short* __restrict__ xi,
                                                const float* __restrict__ xdbl,
                                                const float* __restrict__ dtw,
                                                const float* __restrict__ dtb_,
                                                const float* __restrict__ cw,
                                                const float* __restrict__ cb,
                                                const float* __restrict__ A_log,
                                                float* __restrict__ aprod,
                                                float* __restrict__ hloc) {
    int tid = threadIdx.x;
    int d = blockIdx.x * 256 + tid;
    int b = blockIdx.y, c = blockIdx.z;
    int l0 = c * LC;
    __shared__ float sX[LC][64];
    __shared__ float sW[32][256];
    #pragma unroll
    for (int k = 0; k < 32; ++k)
        sW[k][tid] = dtw[k * 1024 + blockIdx.x * 256 + tid];
    for (int i = tid; i < LC * 64; i += 256) {
        int l = i >> 6, j = i & 63;
        sX[l][j] = xdbl[(size_t)(b * SEQ_L + l0 + l) * 64 + j];
    }
    __syncthreads();
    float A_[D_STATE], h[D_STATE], ap[D_STATE];
    #pragma unroll
    for (int n = 0; n < D_STATE; ++n) {
        A_[n] = -__expf(A_log[(size_t)d * D_STATE + n]);
        h[n] = 0.f; ap[n] = 1.f;
    }
    float4 w = *(const float4*)&cw[d * 4];
    float cbd = cb[d], dtb = dtb_[d];
    const unsigned short* xcol = xi + (size_t)(b * SEQ_L + l0) * 2048 + d;
    float t1 = (l0 >= 1) ? bf2f(xcol[-2048]) : 0.f;
    float t2 = (l0 >= 2) ? bf2f(xcol[-4096]) : 0.f;
    float t3 = (l0 >= 3) ? bf2f(xcol[-6144]) : 0.f;
    for (int l = 0; l < LC; ++l) {
        float dtv = dtb;
        #pragma unroll
        for (int k = 0; k < 32; ++k) dtv = fmaf(sX[l][k], sW[k][tid], dtv);
        dtv = softplus_f(dtv);
        float t0 = bf2f(xcol[l * 2048]);
        float uu = silu_f(cbd + w.x*t3 + w.y*t2 + w.z*t1 + w.w*t0);
        t3 = t2; t2 = t1; t1 = t0;
        float du = dtv * uu;
        #pragma unroll
        for (int n = 0; n < D_STATE; ++n) {
            float e = __expf(dtv * A_[n]);
            h[n] = fmaf(e, h[n], du * sX[l][32 + n]);
            ap[n] *= e;
        }
    }
    #pragma unroll
    for (int n = 0; n < D_STATE; ++n) {
        size_t o = (((size_t)b * NC + c) * D_STATE + n) * D_INNER + d;
        aprod[o] = ap[n];
        hloc[o] = h[n];
    }
}

__global__ __launch_bounds__(256) void scan_p2(const float* __restrict__ aprod,
                                               float* __restrict__ hloc) {
    int d = blockIdx.x * 256 + threadIdx.x;
    int n = blockIdx.y;
    int b = blockIdx.z;
    float h = 0.f;
    for (int c = 0; c < NC; ++c) {
        size_t o = (((size_t)b * NC + c) * D_STATE + n) * D_INNER + d;
        float ap = aprod[o];
        float lc = hloc[o];
        hloc[o] = h;
        h = fmaf(ap, h, lc);
    }
}

__global__ __launch_bounds__(256) void scan_p3f(const unsigned short* __restrict__ xi,
                                                const float* __restrict__ xdbl,
                                                const float* __restrict__ dtw,
                                                const float* __restrict__ dtb_,
                                                const float* __restrict__ cw,
                                                const float* __restrict__ cb,
                                                const float* __restrict__ A_log,
                                                const float* __restrict__ Dp,
                                                const float* __restrict__ hinit,
                                                unsigned short* __restrict__ y) {
    int tid = threadIdx.x;
    int d = blockIdx.x * 256 + tid;
    int b = blockIdx.y, c = blockIdx.z;
    int l0 = c * LC;
    __shared__ float sX[LC][64];
    __shared__ float sW[32][256];
    #pragma unroll
    for (int k = 0; k < 32; ++k)
        sW[k][tid] = dtw[k * 1024 + blockIdx.x * 256 + tid];
    for (int i = tid; i < LC * 64; i += 256) {
        int l = i >> 6, j = i & 63;
        sX[l][j] = xdbl[(size_t)(b * SEQ_L + l0 + l) * 64 + j];
    }
    __syncthreads();
    float A_[D_STATE], h[D_STATE];
    #pragma unroll
    for (int n = 0; n < D_STATE; ++n) {
        A_[n] = -__expf(A_log[(size_t)d * D_STATE + n]);
        size_t o = (((size_t)b * NC + c) * D_STATE + n) * D_INNER + d;
        h[n] = hinit[o];
    }
    float Dd = Dp[d];
    float4 w = *(const float4*)&cw[d * 4];
    float cbd = cb[d], dtb = dtb_[d];
    const unsigned short* xcol = xi + (size_t)(b * SEQ_L + l0) * 2048 + d;
    float t1 = (l0 >= 1) ? bf2f(xcol[-2048]) : 0.f;
    float t2 = (l0 >= 2) ? bf2f(xcol[-4096]) : 0.f;
    float t3 = (l0 >= 3) ? bf2f(xcol[-6144]) : 0.f;
    for (int l = 0; l < LC; ++l) {
        float dtv = dtb;
        #pragma unroll
        for (int k = 0; k < 32; ++k) dtv = fmaf(sX[l][k], sW[k][tid], dtv);
        dtv = softplus_f(dtv);
        float t0 = bf2f(xcol[l * 2048]);
        float uu = silu_f(cbd + w.x*t3 + w.y*t2 + w.z*t1 + w.w*t0);
        t3 = t2; t2 = t1; t1 = t0;
        float du = dtv * uu;
        float yv = 0.f;
        #pragma unroll
        for (int n = 0; n < D_STATE; ++n) {
            float e = __expf(dtv * A_[n]);
            h[n] = fmaf(e, h[n], du * sX[l][32 + n]);
            yv = fmaf(h[n], sX[l][48 + n], yv);
        }
        yv = fmaf(uu, Dd, yv);
        float res = bf2f(xcol[l * 2048 + 1024]);
        y[(size_t)(b * SEQ_L + l0 + l) * D_INNER + d] = f2bf(yv * silu_f(res));
    }
}

// ============== fused final rmsnorm + mean-pool (chunked over L) ============
__global__ __launch_bounds__(256) void rms_pool1(const float* __restrict__ x,
                                                 float* __restrict__ partial) {
    int blk = blockIdx.x;
    int b = blk >> 5, c = blk & 31;
    int wave = threadIdx.x >> 6, lane = threadIdx.x & 63;
    int row0 = b * SEQ_L + c * 32 + wave * 8;
    float4 a0 = make_float4(0.f, 0.f, 0.f, 0.f);
    float4 a1 = make_float4(0.f, 0.f, 0.f, 0.f);
    for (int r = 0; r < 8; ++r) {
        const float* xp = x + (size_t)(row0 + r) * D_MODEL;
        float4 v0 = *(const float4*)&xp[lane * 4];
        float4 v1 = *(const float4*)&xp[256 + lane * 4];
        float ss = v0.x*v0.x + v0.y*v0.y + v0.z*v0.z + v0.w*v0.w
                 + v1.x*v1.x + v1.y*v1.y + v1.z*v1.z + v1.w*v1.w;
        #pragma unroll
        for (int off = 32; off > 0; off >>= 1) ss += __shfl_xor(ss, off);
        float s = rsqrtf(ss * (1.f / D_MODEL) + 1e-5f);
        a0.x = fmaf(v0.x, s, a0.x); a0.y = fmaf(v0.y, s, a0.y);
        a0.z = fmaf(v0.z, s, a0.z); a0.w = fmaf(v0.w, s, a0.w);
        a1.x = fmaf(v1.x, s, a1.x); a1.y = fmaf(v1.y, s, a1.y);
        a1.z = fmaf(v1.z, s, a1.z); a1.w = fmaf(v1.w, s, a1.w);
    }
    __shared__ float red[4][512];
    *(float4*)&red[wave][lane * 4] = a0;
    *(float4*)&red[wave][256 + lane * 4] = a1;
    __syncthreads();
    int d = threadIdx.x * 2;
    float s0 = red[0][d] + red[1][d] + red[2][d] + red[3][d];
    float s1 = red[0][d+1] + red[1][d+1] + red[2][d+1] + red[3][d+1];
    partial[(size_t)blk * 512 + d]     = s0;
    partial[(size_t)blk * 512 + d + 1] = s1;
}

// ---- emb_proj with inline pool reduction: k-split partials -----------------
__global__ __launch_bounds__(256) void embp1f(const float* __restrict__ ppart,
                                              const float* __restrict__ w,
                                              const float* __restrict__ pw,
                                              float* __restrict__ partial) {
    int b = blockIdx.x, kc = blockIdx.y;
    int t = threadIdx.x;
    __shared__ float sp[64];
    if (t < 64) {
        int dd = kc * 64 + t;
        float s = 0.f;
        #pragma unroll
        for (int c = 0; c < 32; ++c)
            s += ppart[((size_t)b * 32 + c) * 512 + dd];
        sp[t] = s * (1.f / SEQ_L) * w[dd];
    }
    __syncthreads();
    float acc = 0.f;
    #pragma unroll 8
    for (int i = 0; i < 64; ++i) {
        int k = kc * 64 + i;
        acc = fmaf(sp[i], pw[(size_t)k * 256 + t], acc);
    }
    partial[((size_t)b * 8 + kc) * 256 + t] = acc;
}

// ---- head: emotion_emb reduce + bias, then logits (one block) --------------
__global__ __launch_bounds__(512) void head_kernel(const float* __restrict__ eparts,
                                                   const float* __restrict__ pb,
                                                   const float* __restrict__ cw,
                                                   const float* __restrict__ cb,
                                                   float* __restrict__ out) {
    __shared__ float se[2][256];
    int t = threadIdx.x;
    int b = t >> 8, e = t & 255;
    float s = pb[e];
    #pragma unroll
    for (int kc = 0; kc < 8; ++kc)
        s += eparts[((size_t)b * 8 + kc) * 256 + e];
    out[14 + b * 256 + e] = s;
    se[b][e] = s;
    __syncthreads();
    int wave = t >> 6, lane = t & 63;
    for (int idx = wave; idx < 14; idx += 8) {
        int bb = idx / 7, cc = idx % 7;
        float a = 0.f;
        #pragma unroll
        for (int i = 0; i < 4; ++i) {
            int k = lane + i * 64;
            a = fmaf(se[bb][k], cw[k * 7 + cc], a);
        }
        #pragma unroll
        for (int off = 32; off > 0; off >>= 1) a += __shfl_xor(a, off);
        if (lane == 0) out[bb * 7 + cc] = a + cb[cc];
    }
}

extern "C" void kernel_launch(void* const* d_in, const int* in_sizes, int n_in,
                              void* d_out, int out_size, void* d_ws, size_t ws_size,
                              hipStream_t stream) {
    const int*   ids    = (const int*)d_in[0];
    const float* emb    = (const float*)d_in[1];
    const float* norm_w = (const float*)d_in[2];
    const float* in_w   = (const float*)d_in[3];
    const float* conv_w = (const float*)d_in[4];
    const float* conv_b = (const float*)d_in[5];
    const float* xp_w   = (const float*)d_in[6];
    const float* dt_w   = (const float*)d_in[7];
    const float* dt_b   = (const float*)d_in[8];
    const float* A_log  = (const float*)d_in[9];
    const float* Dp     = (const float*)d_in[10];
    const float* out_w  = (const float*)d_in[11];
    const float* normf  = (const float*)d_in[12];
    const float* proj_w = (const float*)d_in[13];
    const float* proj_b = (const float*)d_in[14];
    const float* cls_w  = (const float*)d_in[15];
    const float* cls_b  = (const float*)d_in[16];
    float* out = (float*)d_out;

    float* ws     = (float*)d_ws;
    float* x      = ws;                      // 1,048,576 f32
    float* xn     = x + 1048576;             // 1,048,576 f32: xn_bf / hloc / ppart
    float* xr     = xn + 1048576;            // 4,194,304 f32: xr_bf uses 1st half
    float* xconvR = xr + 4194304;            // 2,097,152 f32 (free)
    float* xdbl   = xconvR + 2097152;        //   131,072 f32
    float* wreg   = xdbl + 131072;           // 2,097,152 f32: weights bf16
    float* yb     = wreg + 2097152;          // 2,097,152 f32: aprod + yb_bf
    float* eparts = yb + 2097152 + 1024;     //     4,096 f32

    unsigned short* xn_bf  = (unsigned short*)xn;        // dead before hloc use
    float*          hloc   = xn;
    float*          ppart  = xn;
    unsigned short* xr_bf  = (unsigned short*)xr;
    unsigned short* in_wt_all  = (unsigned short*)wreg;              // 2x 1M
    unsigned short* out_wt_all = (unsigned short*)(wreg + 1048576);  // 2x 512K
    float*          aprod  = yb;
    unsigned short* yb_bf  = (unsigned short*)(yb + 1048576);

    embed_kernel<<<1024, 256, 0, stream>>>(ids, emb, x);
    castT_kernel<<<dim3(64, 16, NLAYER), 256, 0, stream>>>(in_w, in_wt_all, 512, 2048);
    castT_kernel<<<dim3(16, 32, NLAYER), 256, 0, stream>>>(out_w, out_wt_all, 1024, 512);

    for (int i = 0; i < NLAYER; ++i) {
        unsigned short* in_wt  = in_wt_all  + (size_t)i * 2048 * 512;
        unsigned short* out_wt = out_wt_all + (size_t)i * 512 * 1024;
        const float* cwi = conv_w + (size_t)i * D_INNER * 4;
        const float* cbi = conv_b + (size_t)i * D_INNER;
        const float* dtwi = dt_w + (size_t)i * DT_RANK * D_INNER;
        const float* dtbi = dt_b + (size_t)i * D_INNER;
        const float* Ali  = A_log + (size_t)i * D_INNER * D_STATE;

        rmsnorm_bf_kernel<<<M_ROWS, 64, 0, stream>>>(x, norm_w + i * D_MODEL, xn_bf);
        gemm_mfma<3><<<dim3(32, 32), 256, 0, stream>>>(
            xn_bf, in_wt, nullptr, xr_bf, 512, 2048);
        xproj_f<<<M_ROWS / 4, 256, 0, stream>>>(
            xr_bf, cwi, cbi, xp_w + (size_t)i * D_INNER * 64, xdbl);
        scan_p1f<<<dim3(4, BATCH, NC), 256, 0, stream>>>(
            xr_bf, xdbl, dtwi, dtbi, cwi, cbi, Ali, aprod, hloc);
        scan_p2<<<dim3(4, D_STATE, BATCH), 256, 0, stream>>>(aprod, hloc);
        scan_p3f<<<dim3(4, BATCH, NC), 256, 0, stream>>>(
            xr_bf, xdbl, dtwi, dtbi, cwi, cbi, Ali,
            Dp + (size_t)i * D_INNER, hloc, yb_bf);
        gemm_mfma<2><<<dim3(8, 32), 256, 0, stream>>>(
            yb_bf, out_wt, x, nullptr, 1024, 512);
    }

    rms_pool1<<<BATCH * 32, 256, 0, stream>>>(x, ppart);
    embp1f<<<dim3(BATCH, 8), 256, 0, stream>>>(ppart, normf, proj_w, eparts);
    head_kernel<<<1, 512, 0, stream>>>(eparts, proj_b, cls_w, cls_b, out);
}

// Round 8
// 244.967 us; speedup vs baseline: 1.0969x; 1.0969x over previous
//
#include <hip/hip_runtime.h>
#include <cstddef>

#define D_MODEL   512
#define D_INNER   1024
#define D_STATE   16
#define DT_RANK   32
#define SEQ_L     1024
#define BATCH     2
#define NLAYER    2
#define M_ROWS    (BATCH * SEQ_L)   // 2048
#define NC        64                // scan chunks
#define LC        (SEQ_L / NC)      // 16 timesteps per chunk

typedef __bf16 bf16x8 __attribute__((ext_vector_type(8)));
typedef float  f32x4  __attribute__((ext_vector_type(4)));

__device__ __forceinline__ float softplus_f(float x) {
    return fmaxf(x, 0.f) + log1pf(expf(-fabsf(x)));
}
__device__ __forceinline__ float silu_f(float x) {
    return x / (1.f + __expf(-x));
}
__device__ __forceinline__ unsigned short f2bf(float f) {
    unsigned u = __float_as_uint(f);
    return (unsigned short)((u + 0x7fffu + ((u >> 16) & 1u)) >> 16);
}
__device__ __forceinline__ float bf2f(unsigned short v) {
    return __uint_as_float(((unsigned)v) << 16);
}
__device__ __forceinline__ unsigned pack_bf2(float lo, float hi) {
    return (unsigned)f2bf(lo) | ((unsigned)f2bf(hi) << 16);
}

// -------- embedding gather --------------------------------------------------
__global__ void embed_kernel(const int* __restrict__ ids,
                             const float* __restrict__ emb,
                             float* __restrict__ x) {
    int g = blockIdx.x * blockDim.x + threadIdx.x;
    int c = (g & 127) << 2;
    int m = g >> 7;
    int row = ids[m];
    *(float4*)&x[(size_t)m * D_MODEL + c] =
        *(const float4*)&emb[(size_t)row * D_MODEL + c];
}

// -------- rmsnorm (bf16 out) ------------------------------------------------
__global__ __launch_bounds__(64) void rmsnorm_bf_kernel(const float* __restrict__ x,
                                                        const float* __restrict__ w,
                                                        unsigned short* __restrict__ out) {
    int row = blockIdx.x;
    int tid = threadIdx.x;
    const float* xp = x + (size_t)row * D_MODEL;
    float4 v0 = *(const float4*)&xp[tid * 4];
    float4 v1 = *(const float4*)&xp[256 + tid * 4];
    float ss = v0.x*v0.x + v0.y*v0.y + v0.z*v0.z + v0.w*v0.w
             + v1.x*v1.x + v1.y*v1.y + v1.z*v1.z + v1.w*v1.w;
    #pragma unroll
    for (int off = 32; off > 0; off >>= 1) ss += __shfl_xor(ss, off);
    float scale = rsqrtf(ss * (1.f / D_MODEL) + 1e-5f);
    float4 w0 = *(const float4*)&w[tid * 4];
    float4 w1 = *(const float4*)&w[256 + tid * 4];
    unsigned short* op = out + (size_t)row * D_MODEL;
    uint2 p0, p1;
    p0.x = pack_bf2(v0.x * scale * w0.x, v0.y * scale * w0.y);
    p0.y = pack_bf2(v0.z * scale * w0.z, v0.w * scale * w0.w);
    p1.x = pack_bf2(v1.x * scale * w1.x, v1.y * scale * w1.y);
    p1.y = pack_bf2(v1.z * scale * w1.z, v1.w * scale * w1.w);
    *(uint2*)&op[tid * 4] = p0;
    *(uint2*)&op[256 + tid * 4] = p1;
}

// ---- cast+transpose weights (batched over layers via z): W[K][N]->Wt[N][K] -
__global__ __launch_bounds__(256) void castT_kernel(const float* __restrict__ W,
                                                    unsigned short* __restrict__ Wt,
                                                    int K, int N) {
    W  += (size_t)blockIdx.z * K * N;
    Wt += (size_t)blockIdx.z * K * N;
    __shared__ float tile[32][33];
    int n0 = blockIdx.x * 32, k0 = blockIdx.y * 32;
    int tx = threadIdx.x & 31, ty = threadIdx.x >> 5;
    #pragma unroll
    for (int i = 0; i < 4; ++i)
        tile[ty + i*8][tx] = W[(size_t)(k0 + ty + i*8) * N + n0 + tx];
    __syncthreads();
    #pragma unroll
    for (int i = 0; i < 4; ++i)
        Wt[(size_t)(n0 + ty + i*8) * K + k0 + tx] = f2bf(tile[tx][ty + i*8]);
}

// ===== 128x128-tile bf16 MFMA GEMM (m97 structure), bf16 output =============
// A[M,K] bf16, Bt[N,K] bf16; 256 threads = 4 waves (2x2), each 64x64 out.
__global__ __launch_bounds__(256) void gemm_mfma128(const unsigned short* __restrict__ A,
                                                    const unsigned short* __restrict__ Bt,
                                                    unsigned short* __restrict__ Cb,
                                                    int K, int ldc) {
    __shared__ unsigned short As[128 * 64];
    __shared__ unsigned short Bs[128 * 64];
    int m0 = blockIdx.y * 128;
    int n0 = blockIdx.x * 128;
    int t = threadIdx.x;
    int lane = t & 63, wave = t >> 6;
    int wr = wave >> 1, wc = wave & 1;
    int srow = t >> 3;          // 0..31
    int sc8  = t & 7;           // col-group of 8 bf16
    f32x4 acc[4][4] = {};

    for (int k0 = 0; k0 < K; k0 += 64) {
        __syncthreads();
        #pragma unroll
        for (int i = 0; i < 4; ++i) {
            int row = i * 32 + srow;
            int csrc = sc8 ^ (row & 7);
            __builtin_amdgcn_global_load_lds(
                (const __attribute__((address_space(1))) void*)
                    &A[(size_t)(m0 + row) * K + k0 + csrc * 8],
                (__attribute__((address_space(3))) void*)
                    &As[row * 64 + sc8 * 8], 16, 0, 0);
            __builtin_amdgcn_global_load_lds(
                (const __attribute__((address_space(1))) void*)
                    &Bt[(size_t)(n0 + row) * K + k0 + csrc * 8],
                (__attribute__((address_space(3))) void*)
                    &Bs[row * 64 + sc8 * 8], 16, 0, 0);
        }
        __syncthreads();
        #pragma unroll
        for (int ks = 0; ks < 2; ++ks) {
            bf16x8 av[4], bv[4];
            #pragma unroll
            for (int f = 0; f < 4; ++f) {
                int ar = wr * 64 + f * 16 + (lane & 15);
                int ac = (ks * 4 + (lane >> 4)) ^ (ar & 7);
                av[f] = *reinterpret_cast<const bf16x8*>(&As[ar * 64 + ac * 8]);
                int br = wc * 64 + f * 16 + (lane & 15);
                int bc = (ks * 4 + (lane >> 4)) ^ (br & 7);
                bv[f] = *reinterpret_cast<const bf16x8*>(&Bs[br * 64 + bc * 8]);
            }
            #pragma unroll
            for (int fm = 0; fm < 4; ++fm)
                #pragma unroll
                for (int fn = 0; fn < 4; ++fn)
                    acc[fm][fn] = __builtin_amdgcn_mfma_f32_16x16x32_bf16(
                        av[fm], bv[fn], acc[fm][fn], 0, 0, 0);
        }
    }
    #pragma unroll
    for (int fm = 0; fm < 4; ++fm)
        #pragma unroll
        for (int fn = 0; fn < 4; ++fn) {
            int row = m0 + wr * 64 + fm * 16 + (lane >> 4) * 4;
            int col = n0 + wc * 64 + fn * 16 + (lane & 15);
            #pragma unroll
            for (int r = 0; r < 4; ++r)
                Cb[(size_t)(row + r) * ldc + col] = f2bf(acc[fm][fn][r]);
        }
}

// -------- 64x64 bf16 MFMA GEMM, f32 accumulate-into-C (out_proj) ------------
__global__ __launch_bounds__(256) void gemm_mfma64_acc(const unsigned short* __restrict__ A,
                                                       const unsigned short* __restrict__ Bt,
                                                       float* __restrict__ C,
                                                       int K, int ldc) {
    __shared__ unsigned short As[64 * 64];
    __shared__ unsigned short Bs[64 * 64];
    int m0 = blockIdx.y * 64;
    int n0 = blockIdx.x * 64;
    int t = threadIdx.x;
    int lane = t & 63, wave = t >> 6;
    int wr = wave >> 1, wc = wave & 1;
    int srow = t >> 3;
    int sc8  = t & 7;
    f32x4 acc[2][2] = {};

    for (int k0 = 0; k0 < K; k0 += 64) {
        __syncthreads();
        #pragma unroll
        for (int i = 0; i < 2; ++i) {
            int row = i * 32 + srow;
            int csrc = sc8 ^ (row & 7);
            __builtin_amdgcn_global_load_lds(
                (const __attribute__((address_space(1))) void*)
                    &A[(size_t)(m0 + row) * K + k0 + csrc * 8],
                (__attribute__((address_space(3))) void*)
                    &As[row * 64 + sc8 * 8], 16, 0, 0);
            __builtin_amdgcn_global_load_lds(
                (const __attribute__((address_space(1))) void*)
                    &Bt[(size_t)(n0 + row) * K + k0 + csrc * 8],
                (__attribute__((address_space(3))) void*)
                    &Bs[row * 64 + sc8 * 8], 16, 0, 0);
        }
        __syncthreads();
        #pragma unroll
        for (int ks = 0; ks < 2; ++ks) {
            bf16x8 av[2], bv[2];
            #pragma unroll
            for (int f = 0; f < 2; ++f) {
                int ar = wr * 32 + f * 16 + (lane & 15);
                int ac = (ks * 4 + (lane >> 4)) ^ (ar & 7);
                av[f] = *reinterpret_cast<const bf16x8*>(&As[ar * 64 + ac * 8]);
                int br = wc * 32 + f * 16 + (lane & 15);
                int bc = (ks * 4 + (lane >> 4)) ^ (br & 7);
                bv[f] = *reinterpret_cast<const bf16x8*>(&Bs[br * 64 + bc * 8]);
            }
            #pragma unroll
            for (int fm = 0; fm < 2; ++fm)
                #pragma unroll
                for (int fn = 0; fn < 2; ++fn)
                    acc[fm][fn] = __builtin_amdgcn_mfma_f32_16x16x32_bf16(
                        av[fm], bv[fn], acc[fm][fn], 0, 0, 0);
        }
    }
    #pragma unroll
    for (int fm = 0; fm < 2; ++fm)
        #pragma unroll
        for (int fn = 0; fn < 2; ++fn) {
            int row = m0 + wr * 32 + fm * 16 + (lane >> 4) * 4;
            int col = n0 + wc * 32 + fn * 16 + (lane & 15);
            #pragma unroll
            for (int r = 0; r < 4; ++r)
                C[(size_t)(row + r) * ldc + col] += acc[fm][fn][r];
        }
}

// -------- conv+SiLU: u = silu(conv(xi)+cb), bf16 out ------------------------
__global__ void conv_bf_kernel(const unsigned short* __restrict__ xi,
                               const float* __restrict__ cw,
                               const float* __restrict__ cb,
                               unsigned short* __restrict__ u) {
    int g = blockIdx.x * blockDim.x + threadIdx.x;  // M*1024
    int d = g & (D_INNER - 1);
    int m = g >> 10;
    int l = m & (SEQ_L - 1);
    float4 w = *(const float4*)&cw[d * 4];
    const unsigned short* col = &xi[(size_t)m * 2048 + d];
    float x3 = bf2f(col[0]);
    float x2 = (l >= 1) ? bf2f(col[-2048]) : 0.f;
    float x1 = (l >= 2) ? bf2f(col[-4096]) : 0.f;
    float x0 = (l >= 3) ? bf2f(col[-6144]) : 0.f;
    u[g] = f2bf(silu_f(cb[d] + w.x*x0 + w.y*x1 + w.z*x2 + w.w*x3));
}

// -------- x_proj: xdbl[M,64] = u[M,1024] @ xp_w, f32 ------------------------
__global__ __launch_bounds__(256) void xproj_kernel(const unsigned short* __restrict__ u,
                                                    const float* __restrict__ Bw,
                                                    float* __restrict__ Cc) {
    __shared__ float Bsh[64][68];
    __shared__ float Ash[4][64];
    int row0 = blockIdx.x * 4;
    int t = threadIdx.x;
    int tr = t >> 6, c = t & 63;
    int kk = t >> 2, cb4 = (t & 3) << 4;
    float acc = 0.f;
    for (int k0 = 0; k0 < 1024; k0 += 64) {
        __syncthreads();
        #pragma unroll
        for (int j = 0; j < 4; ++j) {
            float4 v = *(const float4*)&Bw[(size_t)(k0 + kk) * 64 + cb4 + j * 4];
            *(float4*)&Bsh[kk][cb4 + j * 4] = v;
        }
        Ash[tr][c] = bf2f(u[(size_t)(row0 + tr) * 1024 + k0 + c]);
        __syncthreads();
        #pragma unroll
        for (int k = 0; k < 64; ++k)
            acc = fmaf(Ash[tr][k], Bsh[k][c], acc);
    }
    Cc[(size_t)(row0 + tr) * 64 + c] = acc;
}

// ======================= chunk-parallel selective scan =======================
// dt = softplus(xdbl[:, :32] @ dt_w + dt_b) recomputed identically in p1/p3.
__global__ __launch_bounds__(256) void scan_p1f(const unsigned short* __restrict__ u,
                                                const float* __restrict__ xdbl,
                                                const float* __restrict__ dtw,
                                                const float* __restrict__ dtb_,
                                                const float* __restrict__ A_log,
                                                float* __restrict__ aprod,
                                                float* __restrict__ hloc) {
    int tid = threadIdx.x;
    int d = blockIdx.x * 256 + tid;
    int b = blockIdx.y, c = blockIdx.z;
    int l0 = c * LC;
    __shared__ float sX[LC][64];
    __shared__ float sW[32][256];
    #pragma unroll
    for (int k = 0; k < 32; ++k)
        sW[k][tid] = dtw[k * 1024 + blockIdx.x * 256 + tid];
    for (int i = tid; i < LC * 64; i += 256) {
        int l = i >> 6, j = i & 63;
        sX[l][j] = xdbl[(size_t)(b * SEQ_L + l0 + l) * 64 + j];
    }
    __syncthreads();
    float A_[D_STATE], h[D_STATE], ap[D_STATE];
    #pragma unroll
    for (int n = 0; n < D_STATE; ++n) {
        A_[n] = -__expf(A_log[(size_t)d * D_STATE + n]);
        h[n] = 0.f; ap[n] = 1.f;
    }
    float dtb = dtb_[d];
    const unsigned short* ucol = u + (size_t)(b * SEQ_L + l0) * D_INNER + d;
    for (int l = 0; l < LC; ++l) {
        float dtv = dtb;
        #pragma unroll
        for (int k = 0; k < 32; ++k) dtv = fmaf(sX[l][k], sW[k][tid], dtv);
        dtv = softplus_f(dtv);
        float uu = bf2f(ucol[l * D_INNER]);
        float du = dtv * uu;
        #pragma unroll
        for (int n = 0; n < D_STATE; ++n) {
            float e = __expf(dtv * A_[n]);
            h[n] = fmaf(e, h[n], du * sX[l][32 + n]);
            ap[n] *= e;
        }
    }
    #pragma unroll
    for (int n = 0; n < D_STATE; ++n) {
        size_t o = (((size_t)b * NC + c) * D_STATE + n) * D_INNER + d;
        aprod[o] = ap[n];
        hloc[o] = h[n];
    }
}

__global__ __launch_bounds__(256) void scan_p2(const float* __restrict__ aprod,
                                               float* __restrict__ hloc) {
    int d = blockIdx.x * 256 + threadIdx.x;
    int n = blockIdx.y;
    int b = blockIdx.z;
    float h = 0.f;
    #pragma unroll 4
    for (int c = 0; c < NC; ++c) {
        size_t o = (((size_t)b * NC + c) * D_STATE + n) * D_INNER + d;
        float ap = aprod[o];
        float lc = hloc[o];
        hloc[o] = h;
        h = fmaf(ap, h, lc);
    }
}

__global__ __launch_bounds__(256) void scan_p3f(const unsigned short* __restrict__ u,
                                                const float* __restrict__ xdbl,
                                                const float* __restrict__ dtw,
                                                const float* __restrict__ dtb_,
                                                const float* __restrict__ A_log,
                                                const float* __restrict__ Dp,
                                                const float* __restrict__ hinit,
                                                const unsigned short* __restrict__ xi,
                                                unsigned short* __restrict__ y) {
    int tid = threadIdx.x;
    int d = blockIdx.x * 256 + tid;
    int b = blockIdx.y, c = blockIdx.z;
    int l0 = c * LC;
    __shared__ float sX[LC][64];
    __shared__ float sW[32][256];
    #pragma unroll
    for (int k = 0; k < 32; ++k)
        sW[k][tid] = dtw[k * 1024 + blockIdx.x * 256 + tid];
    for (int i = tid; i < LC * 64; i += 256) {
        int l = i >> 6, j = i & 63;
        sX[l][j] = xdbl[(size_t)(b * SEQ_L + l0 + l) * 64 + j];
    }
    __syncthreads();
    float A_[D_STATE], h[D_STATE];
    #pragma unroll
    for (int n = 0; n < D_STATE; ++n) {
        A_[n] = -__expf(A_log[(size_t)d * D_STATE + n]);
        size_t o = (((size_t)b * NC + c) * D_STATE + n) * D_INNER + d;
        h[n] = hinit[o];
    }
    float Dd = Dp[d];
    float dtb = dtb_[d];
    const unsigned short* ucol = u  + (size_t)(b * SEQ_L + l0) * D_INNER + d;
    const unsigned short* rcol = xi + (size_t)(b * SEQ_L + l0) * 2048 + 1024 + d;
    for (int l = 0; l < LC; ++l) {
        float dtv = dtb;
        #pragma unroll
        for (int k = 0; k < 32; ++k) dtv = fmaf(sX[l][k], sW[k][tid], dtv);
        dtv = softplus_f(dtv);
        float uu = bf2f(ucol[l * D_INNER]);
        float du = dtv * uu;
        float yv = 0.f;
        #pragma unroll
        for (int n = 0; n < D_STATE; ++n) {
            float e = __expf(dtv * A_[n]);
            h[n] = fmaf(e, h[n], du * sX[l][32 + n]);
            yv = fmaf(h[n], sX[l][48 + n], yv);
        }
        yv = fmaf(uu, Dd, yv);
        float res = bf2f(rcol[l * 2048]);
        y[(size_t)(b * SEQ_L + l0 + l) * D_INNER + d] = f2bf(yv * silu_f(res));
    }
}

// ============== fused final rmsnorm + mean-pool (chunked over L) ============
__global__ __launch_bounds__(256) void rms_pool1(const float* __restrict__ x,
                                                 float* __restrict__ partial) {
    int blk = blockIdx.x;
    int b = blk >> 5, c = blk & 31;
    int wave = threadIdx.x >> 6, lane = threadIdx.x & 63;
    int row0 = b * SEQ_L + c * 32 + wave * 8;
    float4 a0 = make_float4(0.f, 0.f, 0.f, 0.f);
    float4 a1 = make_float4(0.f, 0.f, 0.f, 0.f);
    for (int r = 0; r < 8; ++r) {
        const float* xp = x + (size_t)(row0 + r) * D_MODEL;
        float4 v0 = *(const float4*)&xp[lane * 4];
        float4 v1 = *(const float4*)&xp[256 + lane * 4];
        float ss = v0.x*v0.x + v0.y*v0.y + v0.z*v0.z + v0.w*v0.w
                 + v1.x*v1.x + v1.y*v1.y + v1.z*v1.z + v1.w*v1.w;
        #pragma unroll
        for (int off = 32; off > 0; off >>= 1) ss += __shfl_xor(ss, off);
        float s = rsqrtf(ss * (1.f / D_MODEL) + 1e-5f);
        a0.x = fmaf(v0.x, s, a0.x); a0.y = fmaf(v0.y, s, a0.y);
        a0.z = fmaf(v0.z, s, a0.z); a0.w = fmaf(v0.w, s, a0.w);
        a1.x = fmaf(v1.x, s, a1.x); a1.y = fmaf(v1.y, s, a1.y);
        a1.z = fmaf(v1.z, s, a1.z); a1.w = fmaf(v1.w, s, a1.w);
    }
    __shared__ float red[4][512];
    *(float4*)&red[wave][lane * 4] = a0;
    *(float4*)&red[wave][256 + lane * 4] = a1;
    __syncthreads();
    int d = threadIdx.x * 2;
    float s0 = red[0][d] + red[1][d] + red[2][d] + red[3][d];
    float s1 = red[0][d+1] + red[1][d+1] + red[2][d+1] + red[3][d+1];
    partial[(size_t)blk * 512 + d]     = s0;
    partial[(size_t)blk * 512 + d + 1] = s1;
}

// ---- emb_proj with inline pool reduction: k-split partials -----------------
__global__ __launch_bounds__(256) void embp1f(const float* __restrict__ ppart,
                                              const float* __restrict__ w,
                                              const float* __restrict__ pw,
                                              float* __restrict__ partial) {
    int b = blockIdx.x, kc = blockIdx.y;
    int t = threadIdx.x;
    __shared__ float sp[64];
    if (t < 64) {
        int dd = kc * 64 + t;
        float s = 0.f;
        #pragma unroll
        for (int c = 0; c < 32; ++c)
            s += ppart[((size_t)b * 32 + c) * 512 + dd];
        sp[t] = s * (1.f / SEQ_L) * w[dd];
    }
    __syncthreads();
    float acc = 0.f;
    #pragma unroll 8
    for (int i = 0; i < 64; ++i) {
        int k = kc * 64 + i;
        acc = fmaf(sp[i], pw[(size_t)k * 256 + t], acc);
    }
    partial[((size_t)b * 8 + kc) * 256 + t] = acc;
}

// ---- head: emotion_emb reduce + bias, then logits (one block) --------------
__global__ __launch_bounds__(512) void head_kernel(const float* __restrict__ eparts,
                                                   const float* __restrict__ pb,
                                                   const float* __restrict__ cw,
                                                   const float* __restrict__ cb,
                                                   float* __restrict__ out) {
    __shared__ float se[2][256];
    int t = threadIdx.x;
    int b = t >> 8, e = t & 255;
    float s = pb[e];
    #pragma unroll
    for (int kc = 0; kc < 8; ++kc)
        s += eparts[((size_t)b * 8 + kc) * 256 + e];
    out[14 + b * 256 + e] = s;
    se[b][e] = s;
    __syncthreads();
    int wave = t >> 6, lane = t & 63;
    for (int idx = wave; idx < 14; idx += 8) {
        int bb = idx / 7, cc = idx % 7;
        float a = 0.f;
        #pragma unroll
        for (int i = 0; i < 4; ++i) {
            int k = lane + i * 64;
            a = fmaf(se[bb][k], cw[k * 7 + cc], a);
        }
        #pragma unroll
        for (int off = 32; off > 0; off >>= 1) a += __shfl_xor(a, off);
        if (lane == 0) out[bb * 7 + cc] = a + cb[cc];
    }
}

extern "C" void kernel_launch(void* const* d_in, const int* in_sizes, int n_in,
                              void* d_out, int out_size, void* d_ws, size_t ws_size,
                              hipStream_t stream) {
    const int*   ids    = (const int*)d_in[0];
    const float* emb    = (const float*)d_in[1];
    const float* norm_w = (const float*)d_in[2];
    const float* in_w   = (const float*)d_in[3];
    const float* conv_w = (const float*)d_in[4];
    const float* conv_b = (const float*)d_in[5];
    const float* xp_w   = (const float*)d_in[6];
    const float* dt_w   = (const float*)d_in[7];
    const float* dt_b   = (const float*)d_in[8];
    const float* A_log  = (const float*)d_in[9];
    const float* Dp     = (const float*)d_in[10];
    const float* out_w  = (const float*)d_in[11];
    const float* normf  = (const float*)d_in[12];
    const float* proj_w = (const float*)d_in[13];
    const float* proj_b = (const float*)d_in[14];
    const float* cls_w  = (const float*)d_in[15];
    const float* cls_b  = (const float*)d_in[16];
    float* out = (float*)d_out;

    float* p = (float*)d_ws;
    float* x      = p; p += 1 << 20;          // [2048][512] f32
    float* xnr    = p; p += 1 << 20;          // xn_bf / ppart
    float* xrr    = p; p += 2 << 20;          // xr_bf [2048][2048] bf16
    float* urr    = p; p += 1 << 20;          // u_bf  [2048][1024] bf16
    float* xdbl   = p; p += 1 << 17;          // [2048][64] f32
    float* wreg   = p; p += 1572864;          // in_wt x2 (1M f32) + out_wt x2 (512K f32)
    float* aprod  = p; p += 2 << 20;          // [2][64][16][1024] f32
    float* hloc   = p; p += 2 << 20;          // same shape
    float* ybr    = p; p += 1 << 20;          // yb_bf [2048][1024] bf16
    float* eparts = p; p += 4096;

    unsigned short* xn_bf  = (unsigned short*)xnr;
    float*          ppart  = xnr;
    unsigned short* xr_bf  = (unsigned short*)xrr;
    unsigned short* u_bf   = (unsigned short*)urr;
    unsigned short* in_wt_all  = (unsigned short*)wreg;               // 2x 1M ushort
    unsigned short* out_wt_all = (unsigned short*)(wreg + (1 << 20)); // 2x 512K ushort
    unsigned short* yb_bf  = (unsigned short*)ybr;

    embed_kernel<<<1024, 256, 0, stream>>>(ids, emb, x);
    castT_kernel<<<dim3(64, 16, NLAYER), 256, 0, stream>>>(in_w, in_wt_all, 512, 2048);
    castT_kernel<<<dim3(16, 32, NLAYER), 256, 0, stream>>>(out_w, out_wt_all, 1024, 512);

    for (int i = 0; i < NLAYER; ++i) {
        unsigned short* in_wt  = in_wt_all  + (size_t)i * 2048 * 512;
        unsigned short* out_wt = out_wt_all + (size_t)i * 512 * 1024;
        const float* dtwi = dt_w + (size_t)i * DT_RANK * D_INNER;
        const float* dtbi = dt_b + (size_t)i * D_INNER;
        const float* Ali  = A_log + (size_t)i * D_INNER * D_STATE;

        rmsnorm_bf_kernel<<<M_ROWS, 64, 0, stream>>>(x, norm_w + i * D_MODEL, xn_bf);
        gemm_mfma128<<<dim3(2048 / 128, M_ROWS / 128), 256, 0, stream>>>(
            xn_bf, in_wt, xr_bf, 512, 2048);
        conv_bf_kernel<<<(M_ROWS * D_INNER) / 256, 256, 0, stream>>>(
            xr_bf, conv_w + (size_t)i * D_INNER * 4, conv_b + (size_t)i * D_INNER, u_bf);
        xproj_kernel<<<M_ROWS / 4, 256, 0, stream>>>(
            u_bf, xp_w + (size_t)i * D_INNER * 64, xdbl);
        scan_p1f<<<dim3(4, BATCH, NC), 256, 0, stream>>>(
            u_bf, xdbl, dtwi, dtbi, Ali, aprod, hloc);
        scan_p2<<<dim3(4, D_STATE, BATCH), 256, 0, stream>>>(aprod, hloc);
        scan_p3f<<<dim3(4, BATCH, NC), 256, 0, stream>>>(
            u_bf, xdbl, dtwi, dtbi, Ali, Dp + (size_t)i * D_INNER, hloc, xr_bf, yb_bf);
        gemm_mfma64_acc<<<dim3(512 / 64, M_ROWS / 64), 256, 0, stream>>>(
            yb_bf, out_wt, x, 1024, 512);
    }

    rms_pool1<<<BATCH * 32, 256, 0, stream>>>(x, ppart);
    embp1f<<<dim3(BATCH, 8), 256, 0, stream>>>(ppart, normf, proj_w, eparts);
    head_kernel<<<1, 512, 0, stream>>>(eparts, proj_b, cls_w, cls_b, out);
}